// Round 12
// baseline (1598.044 us; speedup 1.0000x reference)
//
#include <hip/hip_runtime.h>

// CUBA Spiking CNN, B=32, T=100.
// R12: two-stage fence-free pipeline (64 blocks).
//  Stage A [0,32): conv1 + conv2(MFMA f16 hi/lo) + pool -> nibble counts via
//                  WT relaxed agent atomics; flag every 4 steps (R10 proven).
//  Stage C [32,64): per 4-step chunk: conv3 dense (weights once), LIF3 x4,
//                  *** tc via dense f16 hi/lo MFMA (197KB/step vs 540KB sparse),
//                  A-fragments built from hist bitmasks in-register ***, LIF4 x4;
//                  per-step core: {rec 8 waves || fc1(t-1) 8 waves} ->
//                  {LIF5 || LIF6(t-1)+acc}. fc1 delayed 1 step (epilogue t=99).
// Fallback to R7 monolithic kernel if ws_size too small.

#define VTH 0.5f

// d_ws dword offsets
#define W2P_OFF  0
#define W3P_OFF  73728
#define TCP_OFF  368640
#define RECP_OFF 565248
#define FC1P_OFF 630784
#define WS_FLOATS 663552
#define P2G_OFF   WS_FLOATS                    // 144 dw per (b,t), nibble counts
#define FLA_OFF   (P2G_OFF + 32 * 100 * 144)   // 800 flags (one per 4 steps)
#define FLAGS_N   800
#define WS_DW_END (FLA_OFF + FLAGS_N)
#define WS_NEED_BYTES ((size_t)WS_DW_END * 4)

typedef __attribute__((ext_vector_type(8))) _Float16 half8v;
typedef __attribute__((ext_vector_type(4))) float f32x4;

__device__ inline unsigned short f2h_bits(float x) {
  union { _Float16 h; unsigned short u; } c; c.h = (_Float16)x; return c.u;
}
__device__ inline float h2f(unsigned short u) {
  union { unsigned short u; _Float16 h; } c; c.u = u; return (float)c.h;
}

__global__ __launch_bounds__(256) void prep_weights(
    const float* __restrict__ w2, const float* __restrict__ w3,
    const float* __restrict__ tcw, const float* __restrict__ recw,
    const float* __restrict__ fc1w, float* __restrict__ ws)
{
  int idx = blockIdx.x * 256 + threadIdx.x;
  if (idx < W3P_OFF) {
    // conv2 f16 hi/lo fragments (16x16x32 B operand)
    int frag = idx >> 8, r = idx & 255;
    int lane = r >> 2, dw = r & 3;
    int half = frag & 1, nt = (frag >> 1) & 7, kt = frag >> 4;
    unsigned out = 0;
    #pragma unroll
    for (int j2 = 0; j2 < 2; ++j2) {
      int j = dw * 2 + j2;
      int oc = nt * 16 + (lane & 15);
      int k = kt * 32 + ((lane >> 4) << 3) + j;
      int c = k & 63, tap = k >> 6;
      float w = w2[(oc * 64 + c) * 9 + tap];
      unsigned short hb = f2h_bits(w);
      unsigned short bits = half ? f2h_bits((w - h2f(hb)) * 4096.f) : hb;
      out |= ((unsigned)bits) << (16 * j2);
    }
    ((unsigned*)ws)[idx] = out;
  } else if (idx < TCP_OFF) {
    int i = idx - W3P_OFF;
    int r = i & 3, ocq = (i >> 2) & 63, k = i >> 8;
    int oc = ocq * 4 + r, c = k & 127, pos9 = k >> 7;
    ws[idx] = w3[(oc * 128 + c) * 9 + pos9];
  } else if (idx < RECP_OFF) {
    // tc f16 hi/lo fragments (16x16x32 B): frag = (kt*16 + nt)*2 + half
    int i = idx - TCP_OFF;
    int frag = i >> 8, r = i & 255;
    int lane = r >> 2, dwi = r & 3;
    int half = frag & 1, nt = (frag >> 1) & 15, kt = frag >> 5;
    unsigned out = 0;
    #pragma unroll
    for (int j2 = 0; j2 < 2; ++j2) {
      int j = dwi * 2 + j2;
      int d = nt * 16 + (lane & 15);
      int kap = kt * 32 + ((lane >> 4) << 3) + j;
      int kk = kap >> 8, c = kap & 255;
      float w = tcw[(kk * 256 + d) * 256 + c];
      unsigned short hb = f2h_bits(w);
      unsigned short bits = half ? f2h_bits((w - h2f(hb)) * 4096.f) : hb;
      out |= ((unsigned)bits) << (16 * j2);
    }
    ((unsigned*)ws)[idx] = out;
  } else if (idx < FC1P_OFF) {
    int i = idx - RECP_OFF;
    int r = i & 3, dq = (i >> 2) & 63, c = i >> 8;
    ws[idx] = recw[(dq * 4 + r) * 256 + c];
  } else if (idx < WS_FLOATS) {
    int i = idx - FC1P_OFF;
    int r = i & 3, dq = (i >> 2) & 31, c = i >> 7;
    ws[idx] = fc1w[(dq * 4 + r) * 256 + c];
  }
}

__global__ __launch_bounds__(256) void zero_flags(float* __restrict__ ws) {
  int i = blockIdx.x * 256 + threadIdx.x;
  if (i < FLAGS_N) ((unsigned*)ws)[FLA_OFF + i] = 0u;
}

// ---------------------------------------------------------------------------
// R12 pipelined kernel: 64 blocks. [0,32)=stage A, [32,64)=stage C.
// ---------------------------------------------------------------------------
__global__ __launch_bounds__(1024, 4) void snn_pipe(
    const float* __restrict__ input, const float* __restrict__ w1g,
    const float* __restrict__ b1g, const float* __restrict__ b2g,
    const float* __restrict__ b3g, const float* __restrict__ tcbg,
    const float* __restrict__ recbg, const float* __restrict__ fc1bg,
    const float* __restrict__ fc2wg, const float* __restrict__ tswg,
    const float* __restrict__ maskg,
    const float* __restrict__ c1sg, const float* __restrict__ c2sg,
    const float* __restrict__ c3sg, const float* __restrict__ tcsg,
    const float* __restrict__ rsg, const float* __restrict__ fsg,
    float* __restrict__ ws, float* __restrict__ out)
{
  const int tid = threadIdx.x;
  const int wv  = tid >> 6;
  const int ln  = tid & 63;
  unsigned* p2g   = (unsigned*)ws + P2G_OFF;
  unsigned* flagA = (unsigned*)ws + FLA_OFF;

  const int b = blockIdx.x & 31;

  if (blockIdx.x < 32) {
    // ======================= STAGE A: conv1 + conv2 + pool ==================
    const half8v* w2h = (const half8v*)ws;
    __shared__ float xt[100];
    __shared__ __align__(16) unsigned short s1b[84 * 64];
    __shared__ unsigned short s2b[36 * 128];
    __shared__ float b2L[128];
    __shared__ unsigned char p2nb[1152];

    const int co = ln, pos0 = wv;
    float w1r[9];
    #pragma unroll
    for (int k = 0; k < 9; ++k) w1r[k] = w1g[co * 9 + k];
    const float b1r = b1g[co];
    float sp1[4], cur1[4], vol1[4];
    #pragma unroll
    for (int j = 0; j < 4; ++j) {
      int pos = pos0 + 16 * j;
      sp1[j]  = c1sg[((0 * 32 + b) * 64 + co) * 64 + pos];
      cur1[j] = c1sg[((1 * 32 + b) * 64 + co) * 64 + pos];
      vol1[j] = c1sg[((2 * 32 + b) * 64 + co) * 64 + pos];
    }
    const int grpB = (wv < 8);
    const int nt2 = grpB ? wv : (wv - 8);
    const int mtA = grpB ? 0 : 2;
    const int mtB = 1;
    const int oc2 = nt2 * 16 + (ln & 15);
    int pybA, pybB;
    {
      int pA = mtA * 16 + (ln & 15);
      int pB = mtB * 16 + (ln & 15);
      pybA = (pA < 36) ? ((pA / 6) * 8 + (pA % 6)) : 64;
      pybB = (pB / 6) * 8 + (pB % 6);
    }
    float cur2[2][4], vol2[2][4];
    #pragma unroll
    for (int m = 0; m < 2; ++m) {
      int mt = m ? mtB : mtA;
      bool use = (m == 0) || grpB;
      #pragma unroll
      for (int r = 0; r < 4; ++r) {
        int p = mt * 16 + ((ln >> 4) << 2) + r;
        if (use && p < 36) {
          cur2[m][r] = c2sg[((1 * 32 + b) * 128 + oc2) * 36 + p];
          vol2[m][r] = c2sg[((2 * 32 + b) * 128 + oc2) * 36 + p];
        } else { cur2[m][r] = 0.f; vol2[m][r] = 0.f; }
      }
    }
    if (tid < 128) b2L[tid] = b2g[tid];
    if (tid < 640) ((unsigned*)s1b)[64 * 32 + tid] = 0u;
    __syncthreads();

    for (int t = 0; t < 100; ++t) {
      if (tid < 100) xt[tid] = input[(b * 100 + tid) * 100 + t];
      __syncthreads();

      // conv1 + LIF1
      #pragma unroll
      for (int j = 0; j < 4; ++j) {
        int pos = pos0 + 16 * j;
        int y = pos >> 3, x = pos & 7;
        float psp = b1r;
        #pragma unroll
        for (int kk = 0; kk < 9; ++kk) {
          int ky = kk / 3, kx = kk - ky * 3;
          psp = fmaf(xt[(y + ky) * 10 + x + kx], w1r[kk], psp);
        }
        float cur = 0.5f * cur1[j] + psp;
        float vol = 0.75f * vol1[j] * (1.f - sp1[j]) + cur;
        float sp  = (vol > VTH) ? 1.f : 0.f;
        cur1[j] = cur; vol1[j] = vol; sp1[j] = sp;
        unsigned short bits = (vol > VTH) ? (unsigned short)0x3C00 : (unsigned short)0;
        int byte = ((pos << 7) + (co << 1)) ^ ((pos & 7) << 4);
        *(unsigned short*)((char*)s1b + byte) = bits;
      }
      __syncthreads();

      // conv2 MFMA (f16 scaled hi/lo split)
      {
        f32x4 acchA = {0,0,0,0}, acclA = {0,0,0,0};
        f32x4 acchB = {0,0,0,0}, acclB = {0,0,0,0};
        const int lnq16 = (ln >> 4) << 4;
        if (grpB) {
          #pragma unroll
          for (int kt = 0; kt < 18; ++kt) {
            const int tap = kt >> 1;
            const int dpos = (tap / 3) * 8 + (tap % 3);
            const int c0b = ((kt & 1) << 6) + lnq16;
            int posA = pybA + dpos, posB = pybB + dpos;
            int abA = ((posA << 7) + c0b) ^ ((posA & 7) << 4);
            int abB = ((posB << 7) + c0b) ^ ((posB & 7) << 4);
            half8v a0 = *(const half8v*)((const char*)s1b + abA);
            half8v a1 = *(const half8v*)((const char*)s1b + abB);
            half8v bh = w2h[(((kt << 3) + nt2) << 1) * 64 + ln];
            half8v bl = w2h[((((kt << 3) + nt2) << 1) + 1) * 64 + ln];
            acchA = __builtin_amdgcn_mfma_f32_16x16x32_f16(a0, bh, acchA, 0, 0, 0);
            acclA = __builtin_amdgcn_mfma_f32_16x16x32_f16(a0, bl, acclA, 0, 0, 0);
            acchB = __builtin_amdgcn_mfma_f32_16x16x32_f16(a1, bh, acchB, 0, 0, 0);
            acclB = __builtin_amdgcn_mfma_f32_16x16x32_f16(a1, bl, acclB, 0, 0, 0);
          }
        } else {
          #pragma unroll
          for (int kt = 0; kt < 18; ++kt) {
            const int tap = kt >> 1;
            const int dpos = (tap / 3) * 8 + (tap % 3);
            const int c0b = ((kt & 1) << 6) + lnq16;
            int posA = pybA + dpos;
            int abA = ((posA << 7) + c0b) ^ ((posA & 7) << 4);
            half8v a0 = *(const half8v*)((const char*)s1b + abA);
            half8v bh = w2h[(((kt << 3) + nt2) << 1) * 64 + ln];
            half8v bl = w2h[((((kt << 3) + nt2) << 1) + 1) * 64 + ln];
            acchA = __builtin_amdgcn_mfma_f32_16x16x32_f16(a0, bh, acchA, 0, 0, 0);
            acclA = __builtin_amdgcn_mfma_f32_16x16x32_f16(a0, bl, acclA, 0, 0, 0);
          }
        }
        float bias2 = b2L[oc2];
        #pragma unroll
        for (int m = 0; m < 2; ++m) {
          if (m == 1 && !grpB) break;
          int mt = m ? mtB : mtA;
          #pragma unroll
          for (int r = 0; r < 4; ++r) {
            int p = mt * 16 + ((ln >> 4) << 2) + r;
            if (p < 36) {
              float hi = m ? acchB[r] : acchA[r];
              float lo = m ? acclB[r] : acclA[r];
              float psp = hi + 0.000244140625f * lo + bias2;
              float spo = (vol2[m][r] > VTH) ? 1.f : 0.f;
              float cur = 0.5f * cur2[m][r] + psp;
              float vol = 0.75f * vol2[m][r] * (1.f - spo) + cur;
              cur2[m][r] = cur; vol2[m][r] = vol;
              s2b[p * 128 + oc2] = (vol > VTH) ? (unsigned short)0x3C00 : (unsigned short)0;
            }
          }
        }
      }
      __syncthreads();

      // pool: spike-count nibbles (pooled value = n * 0.25, exact)
      if (tid < 576) {
        int pp = tid >> 6, c0 = 2 * (tid & 63);
        int sy = (pp / 3) * 2, sx = (pp % 3) * 2;
        int n0 = (s2b[(sy * 6 + sx) * 128 + c0] != 0) + (s2b[(sy * 6 + sx + 1) * 128 + c0] != 0)
               + (s2b[((sy + 1) * 6 + sx) * 128 + c0] != 0) + (s2b[((sy + 1) * 6 + sx + 1) * 128 + c0] != 0);
        int c1 = c0 + 1;
        int n1 = (s2b[(sy * 6 + sx) * 128 + c1] != 0) + (s2b[(sy * 6 + sx + 1) * 128 + c1] != 0)
               + (s2b[((sy + 1) * 6 + sx) * 128 + c1] != 0) + (s2b[((sy + 1) * 6 + sx + 1) * 128 + c1] != 0);
        p2nb[pp * 128 + c0] = (unsigned char)n0;
        p2nb[pp * 128 + c1] = (unsigned char)n1;
      }
      __syncthreads();
      if (tid < 144) {
        unsigned dwv = 0;
        #pragma unroll
        for (int j = 0; j < 8; ++j)
          dwv |= ((unsigned)p2nb[8 * tid + j] & 0xFu) << (4 * j);
        __hip_atomic_store(&p2g[(b * 100 + t) * 144 + tid], dwv,
                           __ATOMIC_RELAXED, __HIP_MEMORY_SCOPE_AGENT);
      }
      if ((t & 3) == 3) {
        asm volatile("s_waitcnt vmcnt(0)" ::: "memory");
        __syncthreads();
        if (tid == 0)
          __hip_atomic_store(&flagA[b * 25 + (t >> 2)], 1u,
                             __ATOMIC_RELAXED, __HIP_MEMORY_SCOPE_AGENT);
      }
    }
  } else {
    // ===== STAGE C: chunked conv3/LIF3/tc-MFMA/LIF4 + per-step rec/fc ======
    const float4* w3p  = (const float4*)(ws + W3P_OFF);
    const half8v* tcf  = (const half8v*)(ws + TCP_OFF);
    const float4* recp = (const float4*)(ws + RECP_OFF);
    const float4* fc1p = (const float4*)(ws + FC1P_OFF);

    __shared__ float p2L[4][1152];
    __shared__ float psp3[4][256];
    __shared__ float psp3t[4][256];
    __shared__ __align__(16) float scratch[8192];
    __shared__ __align__(16) float scrR[2048];
    __shared__ __align__(16) float scrF[2048];
    __shared__ unsigned histQ32[6][8];       // rows t0-2 .. t0+3, 8 dw each
    __shared__ unsigned long long s5B[4];
    __shared__ float b3L[256], tcbL[768], recbL[256], fc1bL[128];
    __shared__ float fc2wL[256], maskL[128], tswL[100];
    __shared__ float wpart[2][2];

    float c3sp = 0.f, c3cur = 0.f, c3vol = 0.f;
    float tcsp = 0.f, tccur = 0.f, tcvol = 0.f;
    float rspv = 0.f, rcur = 0.f, rvol = 0.f;
    float fsp = 0.f, fcur = 0.f, fvol = 0.f;
    float s4r[4] = {0.f, 0.f, 0.f, 0.f};
    float accR0 = 0.f, accR1 = 0.f;

    if (tid < 256) {
      c3sp  = c3sg[(0 * 32 + b) * 256 + tid];
      c3cur = c3sg[(1 * 32 + b) * 256 + tid];
      c3vol = c3sg[(2 * 32 + b) * 256 + tid];
      tcsp  = tcsg[(0 * 32 + b) * 256 + tid];
      tccur = tcsg[(1 * 32 + b) * 256 + tid];
      tcvol = tcsg[(2 * 32 + b) * 256 + tid];
      rspv  = rsg[(0 * 32 + b) * 256 + tid];
      rcur  = rsg[(1 * 32 + b) * 256 + tid];
      rvol  = rsg[(2 * 32 + b) * 256 + tid];
      b3L[tid]   = b3g[tid];
      recbL[tid] = recbg[tid];
      tcbL[tid]       = tcbg[tid];
      tcbL[256 + tid] = tcbg[256 + tid];
      tcbL[512 + tid] = tcbg[512 + tid];
      unsigned long long bl = __ballot(rspv != 0.f);
      if (ln == 0) s5B[wv] = bl;
    } else if (tid < 384) {
      int d = tid - 256;
      fsp  = fsg[(0 * 32 + b) * 128 + d];
      fcur = fsg[(1 * 32 + b) * 128 + d];
      fvol = fsg[(2 * 32 + b) * 128 + d];
    }
    if (tid < 128) {
      fc1bL[tid] = fc1bg[tid];
      maskL[tid] = maskg[b * 128 + tid];
      fc2wL[tid]       = fc2wg[tid];
      fc2wL[128 + tid] = fc2wg[128 + tid];
    }
    if (tid < 100) tswL[tid] = tswg[tid];
    if (tid < 16) histQ32[tid >> 3][tid & 7] = 0u;   // rows t-2, t-1 = 0
    __syncthreads();

    for (int t0 = 0; t0 < 100; t0 += 4) {
      // ---- chunk head: wait flag, shift hist ring, load 4 steps of p2 ----
      if (tid == 0) {
        unsigned* f = &flagA[b * 25 + (t0 >> 2)];
        int guard = 0;
        while (__hip_atomic_load(f, __ATOMIC_RELAXED, __HIP_MEMORY_SCOPE_AGENT) == 0u) {
          __builtin_amdgcn_s_sleep(8);
          if (++guard > 4000000) break;
        }
      }
      __syncthreads();
      if (t0 > 0 && tid < 16)
        histQ32[tid >> 3][tid & 7] = histQ32[4 + (tid >> 3)][tid & 7];
      if (tid < 576) {
        #pragma unroll
        for (int s = 0; s < 4; ++s) {
          unsigned dwv = __hip_atomic_load(&p2g[((b * 100 + t0) + s) * 144 + (tid >> 2)],
                                           __ATOMIC_RELAXED, __HIP_MEMORY_SCOPE_AGENT);
          int sh = (tid & 3) * 8;
          p2L[s][2 * tid]     = 0.25f * (float)((dwv >> sh) & 0xF);
          p2L[s][2 * tid + 1] = 0.25f * (float)((dwv >> (sh + 4)) & 0xF);
        }
      }
      __syncthreads();

      // ---- conv3: dense, weights read once per chunk ----
      float4 a0 = {0,0,0,0}, a1 = {0,0,0,0}, a2 = {0,0,0,0}, a3 = {0,0,0,0};
      {
        int base = wv * 72;
        #pragma unroll 8
        for (int i = 0; i < 72; ++i) {
          int k = base + i;
          float4 w = w3p[k * 64 + ln];
          float v0 = p2L[0][k], v1 = p2L[1][k], v2 = p2L[2][k], v3 = p2L[3][k];
          a0.x = fmaf(v0, w.x, a0.x); a0.y = fmaf(v0, w.y, a0.y);
          a0.z = fmaf(v0, w.z, a0.z); a0.w = fmaf(v0, w.w, a0.w);
          a1.x = fmaf(v1, w.x, a1.x); a1.y = fmaf(v1, w.y, a1.y);
          a1.z = fmaf(v1, w.z, a1.z); a1.w = fmaf(v1, w.w, a1.w);
          a2.x = fmaf(v2, w.x, a2.x); a2.y = fmaf(v2, w.y, a2.y);
          a2.z = fmaf(v2, w.z, a2.z); a2.w = fmaf(v2, w.w, a2.w);
          a3.x = fmaf(v3, w.x, a3.x); a3.y = fmaf(v3, w.y, a3.y);
          a3.z = fmaf(v3, w.z, a3.z); a3.w = fmaf(v3, w.w, a3.w);
        }
      }
      ((float4*)scratch)[wv * 64 + ln] = a0;
      ((float4*)(scratch + 4096))[wv * 64 + ln] = a1;
      __syncthreads();
      if (tid < 256) {
        float s0 = b3L[tid], s1 = b3L[tid];
        #pragma unroll
        for (int ks = 0; ks < 16; ++ks) {
          s0 += scratch[ks * 256 + tid];
          s1 += scratch[4096 + ks * 256 + tid];
        }
        psp3[0][tid] = s0; psp3[1][tid] = s1;
      }
      __syncthreads();
      ((float4*)scratch)[wv * 64 + ln] = a2;
      ((float4*)(scratch + 4096))[wv * 64 + ln] = a3;
      __syncthreads();
      if (tid < 256) {
        float s2 = b3L[tid], s3 = b3L[tid];
        #pragma unroll
        for (int ks = 0; ks < 16; ++ks) {
          s2 += scratch[ks * 256 + tid];
          s3 += scratch[4096 + ks * 256 + tid];
        }
        psp3[2][tid] = s2; psp3[3][tid] = s3;
      }
      __syncthreads();

      // ---- LIF3 x4 -> histQ32 rows 2..5 ----
      if (tid < 256) {
        #pragma unroll
        for (int s = 0; s < 4; ++s) {
          float cur = 0.5f * c3cur + psp3[s][tid];
          float vol = 0.75f * c3vol * (1.f - c3sp) + cur;
          float sp  = (vol > VTH) ? 1.f : 0.f;
          c3cur = cur; c3vol = vol; c3sp = sp;
          unsigned long long bl = __ballot(sp != 0.f);
          if (ln == 0) {
            histQ32[2 + s][wv * 2]     = (unsigned)bl;
            histQ32[2 + s][wv * 2 + 1] = (unsigned)(bl >> 32);
          }
        }
      }
      __syncthreads();

      // ---- tc via dense f16 hi/lo MFMA: M=4 steps(padded 16) N=256 K=768 ----
      {
        f32x4 ach = {0,0,0,0}, acl = {0,0,0,0};
        const int srow = ln & 15;
        const int koff = (ln >> 4) << 3;
        #pragma unroll
        for (int kt = 0; kt < 24; ++kt) {
          int k0 = kt * 32 + koff;
          unsigned bits8 = 0u;
          if (srow < 4)
            bits8 = (histQ32[srow + (k0 >> 8)][(k0 & 255) >> 5] >> (k0 & 31)) & 0xFFu;
          union { unsigned u[4]; half8v h; } av;
          av.u[0] = ((bits8 & 1u)   ? 0x3C00u : 0u) | ((bits8 & 2u)   ? 0x3C000000u : 0u);
          av.u[1] = ((bits8 & 4u)   ? 0x3C00u : 0u) | ((bits8 & 8u)   ? 0x3C000000u : 0u);
          av.u[2] = ((bits8 & 16u)  ? 0x3C00u : 0u) | ((bits8 & 32u)  ? 0x3C000000u : 0u);
          av.u[3] = ((bits8 & 64u)  ? 0x3C00u : 0u) | ((bits8 & 128u) ? 0x3C000000u : 0u);
          half8v bh = tcf[((kt * 16 + wv) * 2) * 64 + ln];
          half8v bl = tcf[((kt * 16 + wv) * 2 + 1) * 64 + ln];
          ach = __builtin_amdgcn_mfma_f32_16x16x32_f16(av.h, bh, ach, 0, 0, 0);
          acl = __builtin_amdgcn_mfma_f32_16x16x32_f16(av.h, bl, acl, 0, 0, 0);
        }
        if (ln < 16) {
          #pragma unroll
          for (int r = 0; r < 4; ++r)
            psp3t[r][wv * 16 + ln] = ach[r] + 0.000244140625f * acl[r];
        }
      }
      __syncthreads();

      // ---- LIF4 x4 -> s4r ----
      if (tid < 256) {
        #pragma unroll
        for (int s = 0; s < 4; ++s) {
          int t = t0 + s;
          float sum = psp3t[s][tid];
          #pragma unroll
          for (int kk = 0; kk < 3; ++kk)
            if (t >= 2 - kk) sum += tcbL[kk * 256 + tid];
          float cur = 0.5f * tccur + sum;
          float vol = 0.75f * tcvol * (1.f - tcsp) + cur;
          float sp  = (vol > VTH) ? 1.f : 0.f;
          tccur = cur; tcvol = vol; tcsp = sp;
          s4r[s] = sp;
        }
      }
      __syncthreads();

      // ---- per-step serial core: 2 barriers/step, all 16 waves busy ----
      #pragma unroll
      for (int s = 0; s < 4; ++s) {
        int t = t0 + s;
        // P_a: rec(t) on waves 0-7 (32-bit half-masks) || fc1(t-1) on waves 8-15
        if (wv < 8) {
          int g = wv >> 1, h = wv & 1;
          unsigned m = (unsigned)(s5B[g] >> (h * 32));
          float4 a = {0.f, 0.f, 0.f, 0.f};
          while (m) {
            int bit = __builtin_ctz(m);
            m &= m - 1;
            float4 w4 = recp[(g * 64 + h * 32 + bit) * 64 + ln];
            a.x += w4.x; a.y += w4.y; a.z += w4.z; a.w += w4.w;
          }
          ((float4*)scrR)[wv * 64 + ln] = a;
        } else if (t > 0) {
          int g2 = wv - 8;
          unsigned m = (unsigned)(s5B[g2 >> 1] >> ((g2 & 1) * 32));
          int jj = ln >> 5, q = ln & 31, i = 0;
          float4 a = {0.f, 0.f, 0.f, 0.f};
          while (m) {
            int bit = __builtin_ctz(m);
            m &= m - 1;
            if ((i & 1) == jj) {
              float4 w4 = fc1p[(g2 * 32 + bit) * 32 + q];
              a.x += w4.x; a.y += w4.y; a.z += w4.z; a.w += w4.w;
            }
            ++i;
          }
          ((float4*)scrF)[(g2 * 2 + jj) * 32 + q] = a;
        }
        __syncthreads();
        // P_b: LIF5(t) on tid<256 || LIF6(t-1)+fc2-acc on tid 256..383
        if (tid < 256) {
          float r = s4r[s] + recbL[tid];
          #pragma unroll
          for (int w = 0; w < 8; ++w) r += scrR[w * 256 + tid];
          float cur = 0.5f * rcur + r;
          float vol = 0.75f * rvol * (1.f - rspv) + cur;
          float sp  = (vol > VTH) ? 1.f : 0.f;
          rcur = cur; rvol = vol; rspv = sp;
          unsigned long long bl = __ballot(sp != 0.f);
          if (ln == 0) s5B[wv] = bl;
        } else if (tid < 384 && t > 0) {
          int d = tid - 256;
          float sum = fc1bL[d];
          #pragma unroll
          for (int sl = 0; sl < 16; ++sl) sum += scrF[sl * 128 + d];
          float cur = (0.5f * fcur + sum) * maskL[d];
          float vol = 0.75f * fvol * (1.f - fsp) + cur;
          float sp  = (vol > VTH) ? 1.f : 0.f;
          fcur = cur; fvol = vol; fsp = sp;
          float v0 = sp * fc2wL[d];
          float v1 = sp * fc2wL[128 + d];
          #pragma unroll
          for (int off = 32; off > 0; off >>= 1) {
            v0 += __shfl_down(v0, off);
            v1 += __shfl_down(v1, off);
          }
          if (ln == 0) {
            float wt = tswL[t - 1];
            accR0 += wt * v0; accR1 += wt * v1;
          }
        }
        __syncthreads();
      }
    }

    // ---- epilogue: fc1 + LIF6 + acc for t = 99 ----
    if (wv >= 8) {
      int g2 = wv - 8;
      unsigned m = (unsigned)(s5B[g2 >> 1] >> ((g2 & 1) * 32));
      int jj = ln >> 5, q = ln & 31, i = 0;
      float4 a = {0.f, 0.f, 0.f, 0.f};
      while (m) {
        int bit = __builtin_ctz(m);
        m &= m - 1;
        if ((i & 1) == jj) {
          float4 w4 = fc1p[(g2 * 32 + bit) * 32 + q];
          a.x += w4.x; a.y += w4.y; a.z += w4.z; a.w += w4.w;
        }
        ++i;
      }
      ((float4*)scrF)[(g2 * 2 + jj) * 32 + q] = a;
    }
    __syncthreads();
    if (tid >= 256 && tid < 384) {
      int d = tid - 256;
      float sum = fc1bL[d];
      #pragma unroll
      for (int sl = 0; sl < 16; ++sl) sum += scrF[sl * 128 + d];
      float cur = (0.5f * fcur + sum) * maskL[d];
      float vol = 0.75f * fvol * (1.f - fsp) + cur;
      float sp  = (vol > VTH) ? 1.f : 0.f;
      float v0 = sp * fc2wL[d];
      float v1 = sp * fc2wL[128 + d];
      #pragma unroll
      for (int off = 32; off > 0; off >>= 1) {
        v0 += __shfl_down(v0, off);
        v1 += __shfl_down(v1, off);
      }
      if (ln == 0) {
        float wt = tswL[99];
        accR0 += wt * v0; accR1 += wt * v1;
        wpart[wv - 4][0] = accR0; wpart[wv - 4][1] = accR1;
      }
    }
    __syncthreads();
    if (tid < 2) out[b * 2 + tid] = wpart[0][tid] + wpart[1][tid];
  }
}

// ---------------------------------------------------------------------------
// R7 monolithic fallback (used when ws_size < WS_NEED_BYTES).
// NOTE: uses the OLD f32 tc layout only through its own code path; since
// prep_weights now writes f16 tc frags, the fallback recomputes tc densely
// from tcw via global reads (correct, slower) — only used when ws too small.
// ---------------------------------------------------------------------------
__global__ __launch_bounds__(1024, 4) void snn_main(
    const float* __restrict__ input, const float* __restrict__ w1g,
    const float* __restrict__ b1g, const float* __restrict__ b2g,
    const float* __restrict__ b3g, const float* __restrict__ tcbg,
    const float* __restrict__ recbg, const float* __restrict__ fc1bg,
    const float* __restrict__ fc2wg, const float* __restrict__ tswg,
    const float* __restrict__ maskg, const float* __restrict__ tcwg,
    const float* __restrict__ c1sg, const float* __restrict__ c2sg,
    const float* __restrict__ c3sg, const float* __restrict__ tcsg,
    const float* __restrict__ rsg, const float* __restrict__ fsg,
    const float* __restrict__ ws, float* __restrict__ out)
{
  const half8v* w2h  = (const half8v*)ws;
  const float4* w3p  = (const float4*)(ws + W3P_OFF);
  const float4* recp = (const float4*)(ws + RECP_OFF);
  const float4* fc1p = (const float4*)(ws + FC1P_OFF);

  const int b   = blockIdx.x;
  const int tid = threadIdx.x;
  const int wv  = tid >> 6;
  const int ln  = tid & 63;

  __shared__ __align__(16) float scratch[4096];
  __shared__ __align__(16) unsigned short s1b[84 * 64];
  __shared__ unsigned short s2b[36 * 128];
  __shared__ float p2f[1152];
  __shared__ float xt[100];
  __shared__ float histf[768];
  __shared__ float s4v[256];
  __shared__ float c3cur[256], c3vol[256], c3sp[256];
  __shared__ float tccur[256], tcvol[256], tcsp[256];
  __shared__ float rcur[256],  rvol[256],  rsp[256];
  __shared__ float fcur[128],  fvol[128],  fsp[128];
  __shared__ float b3L[256], tcbL[768], recbL[256], fc1bL[128];
  __shared__ float fc2wL[256], maskL[128], tswL[100], b2L[128];
  __shared__ float accv[2];
  __shared__ float wpart[2][2];

  const int co = ln, pos0 = wv;
  float w1r[9];
  #pragma unroll
  for (int k = 0; k < 9; ++k) w1r[k] = w1g[co * 9 + k];
  const float b1r = b1g[co];
  float sp1[4], cur1[4], vol1[4];
  #pragma unroll
  for (int j = 0; j < 4; ++j) {
    int pos = pos0 + 16 * j;
    sp1[j]  = c1sg[((0 * 32 + b) * 64 + co) * 64 + pos];
    cur1[j] = c1sg[((1 * 32 + b) * 64 + co) * 64 + pos];
    vol1[j] = c1sg[((2 * 32 + b) * 64 + co) * 64 + pos];
  }
  const int grpB = (wv < 8);
  const int nt2 = grpB ? wv : (wv - 8);
  const int mtA = grpB ? 0 : 2;
  const int mtB = 1;
  const int oc2 = nt2 * 16 + (ln & 15);
  int pybA, pybB;
  {
    int pA = mtA * 16 + (ln & 15);
    int pB = mtB * 16 + (ln & 15);
    pybA = (pA < 36) ? ((pA / 6) * 8 + (pA % 6)) : 64;
    pybB = (pB / 6) * 8 + (pB % 6);
  }
  float cur2[2][4], vol2[2][4];
  #pragma unroll
  for (int m = 0; m < 2; ++m) {
    int mt = m ? mtB : mtA;
    bool use = (m == 0) || grpB;
    #pragma unroll
    for (int r = 0; r < 4; ++r) {
      int p = mt * 16 + ((ln >> 4) << 2) + r;
      if (use && p < 36) {
        cur2[m][r] = c2sg[((1 * 32 + b) * 128 + oc2) * 36 + p];
        vol2[m][r] = c2sg[((2 * 32 + b) * 128 + oc2) * 36 + p];
      } else { cur2[m][r] = 0.f; vol2[m][r] = 0.f; }
    }
  }
  if (tid < 256) {
    c3sp[tid]  = c3sg[(0 * 32 + b) * 256 + tid];
    c3cur[tid] = c3sg[(1 * 32 + b) * 256 + tid];
    c3vol[tid] = c3sg[(2 * 32 + b) * 256 + tid];
    tcsp[tid]  = tcsg[(0 * 32 + b) * 256 + tid];
    tccur[tid] = tcsg[(1 * 32 + b) * 256 + tid];
    tcvol[tid] = tcsg[(2 * 32 + b) * 256 + tid];
    rsp[tid]   = rsg[(0 * 32 + b) * 256 + tid];
    rcur[tid]  = rsg[(1 * 32 + b) * 256 + tid];
    rvol[tid]  = rsg[(2 * 32 + b) * 256 + tid];
    b3L[tid]   = b3g[tid];
    recbL[tid] = recbg[tid];
    tcbL[tid]       = tcbg[tid];
    tcbL[256 + tid] = tcbg[256 + tid];
    tcbL[512 + tid] = tcbg[512 + tid];
    histf[tid] = 0.f; histf[256 + tid] = 0.f; histf[512 + tid] = 0.f;
  }
  if (tid < 128) {
    fsp[tid]   = fsg[(0 * 32 + b) * 128 + tid];
    fcur[tid]  = fsg[(1 * 32 + b) * 128 + tid];
    fvol[tid]  = fsg[(2 * 32 + b) * 128 + tid];
    fc1bL[tid] = fc1bg[tid];
    maskL[tid] = maskg[b * 128 + tid];
    b2L[tid]   = b2g[tid];
    fc2wL[tid]       = fc2wg[tid];
    fc2wL[128 + tid] = fc2wg[128 + tid];
  }
  if (tid < 100) tswL[tid] = tswg[tid];
  if (tid < 640) ((unsigned*)s1b)[64 * 32 + tid] = 0u;
  if (tid == 0) { accv[0] = 0.f; accv[1] = 0.f; }
  __syncthreads();

  for (int t = 0; t < 100; ++t) {
    const int tm3 = t % 3;
    if (tid < 100) xt[tid] = input[(b * 100 + tid) * 100 + t];
    __syncthreads();
    #pragma unroll
    for (int j = 0; j < 4; ++j) {
      int pos = pos0 + 16 * j;
      int y = pos >> 3, x = pos & 7;
      float psp = b1r;
      #pragma unroll
      for (int kk = 0; kk < 9; ++kk) {
        int ky = kk / 3, kx = kk - ky * 3;
        psp = fmaf(xt[(y + ky) * 10 + x + kx], w1r[kk], psp);
      }
      float cur = 0.5f * cur1[j] + psp;
      float vol = 0.75f * vol1[j] * (1.f - sp1[j]) + cur;
      float sp  = (vol > VTH) ? 1.f : 0.f;
      cur1[j] = cur; vol1[j] = vol; sp1[j] = sp;
      unsigned short bits = (vol > VTH) ? (unsigned short)0x3C00 : (unsigned short)0;
      int byte = ((pos << 7) + (co << 1)) ^ ((pos & 7) << 4);
      *(unsigned short*)((char*)s1b + byte) = bits;
    }
    __syncthreads();
    {
      f32x4 acchA = {0,0,0,0}, acclA = {0,0,0,0};
      f32x4 acchB = {0,0,0,0}, acclB = {0,0,0,0};
      const int lnq16 = (ln >> 4) << 4;
      if (grpB) {
        #pragma unroll
        for (int kt = 0; kt < 18; ++kt) {
          const int tap = kt >> 1;
          const int dpos = (tap / 3) * 8 + (tap % 3);
          const int c0b = ((kt & 1) << 6) + lnq16;
          int posA = pybA + dpos, posB = pybB + dpos;
          int abA = ((posA << 7) + c0b) ^ ((posA & 7) << 4);
          int abB = ((posB << 7) + c0b) ^ ((posB & 7) << 4);
          half8v a0 = *(const half8v*)((const char*)s1b + abA);
          half8v a1 = *(const half8v*)((const char*)s1b + abB);
          half8v bh = w2h[(((kt << 3) + nt2) << 1) * 64 + ln];
          half8v bl = w2h[((((kt << 3) + nt2) << 1) + 1) * 64 + ln];
          acchA = __builtin_amdgcn_mfma_f32_16x16x32_f16(a0, bh, acchA, 0, 0, 0);
          acclA = __builtin_amdgcn_mfma_f32_16x16x32_f16(a0, bl, acclA, 0, 0, 0);
          acchB = __builtin_amdgcn_mfma_f32_16x16x32_f16(a1, bh, acchB, 0, 0, 0);
          acclB = __builtin_amdgcn_mfma_f32_16x16x32_f16(a1, bl, acclB, 0, 0, 0);
        }
      } else {
        #pragma unroll
        for (int kt = 0; kt < 18; ++kt) {
          const int tap = kt >> 1;
          const int dpos = (tap / 3) * 8 + (tap % 3);
          const int c0b = ((kt & 1) << 6) + lnq16;
          int posA = pybA + dpos;
          int abA = ((posA << 7) + c0b) ^ ((posA & 7) << 4);
          half8v a0 = *(const half8v*)((const char*)s1b + abA);
          half8v bh = w2h[(((kt << 3) + nt2) << 1) * 64 + ln];
          half8v bl = w2h[((((kt << 3) + nt2) << 1) + 1) * 64 + ln];
          acchA = __builtin_amdgcn_mfma_f32_16x16x32_f16(a0, bh, acchA, 0, 0, 0);
          acclA = __builtin_amdgcn_mfma_f32_16x16x32_f16(a0, bl, acclA, 0, 0, 0);
        }
      }
      float bias2 = b2L[oc2];
      #pragma unroll
      for (int m = 0; m < 2; ++m) {
        if (m == 1 && !grpB) break;
        int mt = m ? mtB : mtA;
        #pragma unroll
        for (int r = 0; r < 4; ++r) {
          int p = mt * 16 + ((ln >> 4) << 2) + r;
          if (p < 36) {
            float hi = m ? acchB[r] : acchA[r];
            float lo = m ? acclB[r] : acclA[r];
            float psp = hi + 0.000244140625f * lo + bias2;
            float spo = (vol2[m][r] > VTH) ? 1.f : 0.f;
            float cur = 0.5f * cur2[m][r] + psp;
            float vol = 0.75f * vol2[m][r] * (1.f - spo) + cur;
            cur2[m][r] = cur; vol2[m][r] = vol;
            s2b[p * 128 + oc2] = (vol > VTH) ? (unsigned short)0x3C00 : (unsigned short)0;
          }
        }
      }
    }
    __syncthreads();
    {
      int c = tid & 127, pp = tid >> 7;
      int sy = (pp / 3) * 2, sx = (pp % 3) * 2;
      float v = h2f(s2b[(sy * 6 + sx) * 128 + c]) + h2f(s2b[(sy * 6 + sx + 1) * 128 + c])
              + h2f(s2b[((sy + 1) * 6 + sx) * 128 + c]) + h2f(s2b[((sy + 1) * 6 + sx + 1) * 128 + c]);
      p2f[pp * 128 + c] = 0.25f * v;
      if (tid < 128) {
        float v8 = h2f(s2b[(4 * 6 + 4) * 128 + c]) + h2f(s2b[(4 * 6 + 5) * 128 + c])
                 + h2f(s2b[(5 * 6 + 4) * 128 + c]) + h2f(s2b[(5 * 6 + 5) * 128 + c]);
        p2f[8 * 128 + c] = 0.25f * v8;
      }
    }
    __syncthreads();
    {
      int ocq = tid & 63, ks = tid >> 6;
      float4 a = {0.f, 0.f, 0.f, 0.f};
      const float4* wrow = w3p + (ks * 72) * 64 + ocq;
      const float* prow = p2f + ks * 72;
      #pragma unroll 8
      for (int i = 0; i < 72; ++i) {
        float pv = prow[i];
        if (pv != 0.f) {
          float4 w = wrow[i * 64];
          a.x = fmaf(pv, w.x, a.x); a.y = fmaf(pv, w.y, a.y);
          a.z = fmaf(pv, w.z, a.z); a.w = fmaf(pv, w.w, a.w);
        }
      }
      ((float4*)scratch)[tid] = a;
    }
    __syncthreads();
    if (tid < 256) {
      int d = tid;
      float s = b3L[d];
      #pragma unroll
      for (int ks = 0; ks < 16; ++ks) s += scratch[ks * 256 + d];
      float cur = 0.5f * c3cur[d] + s;
      float vol = 0.75f * c3vol[d] * (1.f - c3sp[d]) + cur;
      float sp  = (vol > VTH) ? 1.f : 0.f;
      c3cur[d] = cur; c3vol[d] = vol; c3sp[d] = sp;
      histf[tm3 * 256 + d] = sp;
    }
    __syncthreads();
    {
      // tc via direct tcw reads (fallback path only)
      int dq = tid & 63, ks = tid >> 6;
      float4 a = {0.f, 0.f, 0.f, 0.f};
      #pragma unroll 4
      for (int i = 0; i < 48; ++i) {
        int k = ks * 48 + i;
        int kk = k >> 8;
        int vv = tm3 + 1 + kk; if (vv >= 3) vv -= 3;
        float hv = histf[(vv << 8) + (k & 255)];
        if (hv != 0.f) {
          int c = k & 255;
          a.x = fmaf(hv, tcwg[(kk * 256 + dq * 4 + 0) * 256 + c], a.x);
          a.y = fmaf(hv, tcwg[(kk * 256 + dq * 4 + 1) * 256 + c], a.y);
          a.z = fmaf(hv, tcwg[(kk * 256 + dq * 4 + 2) * 256 + c], a.z);
          a.w = fmaf(hv, tcwg[(kk * 256 + dq * 4 + 3) * 256 + c], a.w);
        }
      }
      ((float4*)scratch)[tid] = a;
    }
    __syncthreads();
    if (tid < 256) {
      int d = tid;
      float s = 0.f;
      #pragma unroll
      for (int ks = 0; ks < 16; ++ks) s += scratch[ks * 256 + d];
      #pragma unroll
      for (int kk = 0; kk < 3; ++kk)
        if (t >= 2 - kk) s += tcbL[kk * 256 + d];
      float cur = 0.5f * tccur[d] + s;
      float vol = 0.75f * tcvol[d] * (1.f - tcsp[d]) + cur;
      float sp  = (vol > VTH) ? 1.f : 0.f;
      tccur[d] = cur; tcvol[d] = vol; tcsp[d] = sp;
      s4v[d] = sp;
    }
    __syncthreads();
    {
      int dq = tid & 63, ks = tid >> 6;
      float4 a = {0.f, 0.f, 0.f, 0.f};
      const float4* wrow = recp + (ks * 16) * 64 + dq;
      const float* hr = rsp + ks * 16;
      #pragma unroll
      for (int i = 0; i < 16; ++i) {
        float hv = hr[i];
        if (hv != 0.f) {
          float4 w = wrow[i * 64];
          a.x = fmaf(hv, w.x, a.x); a.y = fmaf(hv, w.y, a.y);
          a.z = fmaf(hv, w.z, a.z); a.w = fmaf(hv, w.w, a.w);
        }
      }
      ((float4*)scratch)[tid] = a;
    }
    __syncthreads();
    if (tid < 256) {
      int d = tid;
      float s = s4v[d] + recbL[d];
      #pragma unroll
      for (int ks = 0; ks < 16; ++ks) s += scratch[ks * 256 + d];
      float cur = 0.5f * rcur[d] + s;
      float vol = 0.75f * rvol[d] * (1.f - rsp[d]) + cur;
      float sp  = (vol > VTH) ? 1.f : 0.f;
      rcur[d] = cur; rvol[d] = vol; rsp[d] = sp;
    }
    __syncthreads();
    {
      int dq = tid & 31, ks = tid >> 5;
      float4 a = {0.f, 0.f, 0.f, 0.f};
      const float4* wrow = fc1p + (ks * 8) * 32 + dq;
      const float* hr = rsp + ks * 8;
      #pragma unroll
      for (int i = 0; i < 8; ++i) {
        float hv = hr[i];
        if (hv != 0.f) {
          float4 w = wrow[i * 32];
          a.x = fmaf(hv, w.x, a.x); a.y = fmaf(hv, w.y, a.y);
          a.z = fmaf(hv, w.z, a.z); a.w = fmaf(hv, w.w, a.w);
        }
      }
      ((float4*)scratch)[tid] = a;
    }
    __syncthreads();
    if (tid < 128) {
      int d = tid;
      float s = fc1bL[d];
      #pragma unroll
      for (int ks = 0; ks < 32; ++ks) s += scratch[ks * 128 + d];
      float cur = (0.5f * fcur[d] + s) * maskL[d];
      float vol = 0.75f * fvol[d] * (1.f - fsp[d]) + cur;
      float sp  = (vol > VTH) ? 1.f : 0.f;
      fcur[d] = cur; fvol[d] = vol; fsp[d] = sp;
      float v0 = sp * fc2wL[d];
      float v1 = sp * fc2wL[128 + d];
      #pragma unroll
      for (int off = 32; off > 0; off >>= 1) {
        v0 += __shfl_down(v0, off);
        v1 += __shfl_down(v1, off);
      }
      if ((tid & 63) == 0) { wpart[tid >> 6][0] = v0; wpart[tid >> 6][1] = v1; }
    }
    __syncthreads();
    if (tid == 0) {
      float wt = tswL[t];
      accv[0] += wt * (wpart[0][0] + wpart[1][0]);
      accv[1] += wt * (wpart[0][1] + wpart[1][1]);
    }
  }
  __syncthreads();
  if (tid < 2) out[b * 2 + tid] = accv[tid];
}

extern "C" void kernel_launch(void* const* d_in, const int* in_sizes, int n_in,
                              void* d_out, int out_size, void* d_ws, size_t ws_size,
                              hipStream_t stream) {
  const float* input = (const float*)d_in[0];
  const float* w1    = (const float*)d_in[1];
  const float* b1    = (const float*)d_in[2];
  const float* w2    = (const float*)d_in[3];
  const float* b2    = (const float*)d_in[4];
  const float* w3    = (const float*)d_in[5];
  const float* b3    = (const float*)d_in[6];
  const float* tcw   = (const float*)d_in[7];
  const float* tcb   = (const float*)d_in[8];
  const float* recw  = (const float*)d_in[9];
  const float* recb  = (const float*)d_in[10];
  const float* fc1w  = (const float*)d_in[11];
  const float* fc1b  = (const float*)d_in[12];
  const float* fc2w  = (const float*)d_in[13];
  const float* tsw   = (const float*)d_in[14];
  const float* mask  = (const float*)d_in[15];
  const float* c1s   = (const float*)d_in[16];
  const float* c2s   = (const float*)d_in[17];
  const float* c3s   = (const float*)d_in[18];
  const float* tcs   = (const float*)d_in[19];
  const float* rs    = (const float*)d_in[20];
  const float* fs    = (const float*)d_in[21];
  float* ws   = (float*)d_ws;
  float* outp = (float*)d_out;

  prep_weights<<<WS_FLOATS / 256, 256, 0, stream>>>(w2, w3, tcw, recw, fc1w, ws);
  if (ws_size >= WS_NEED_BYTES) {
    zero_flags<<<(FLAGS_N + 255) / 256, 256, 0, stream>>>(ws);
    snn_pipe<<<64, 1024, 0, stream>>>(input, w1, b1, b2, b3, tcb, recb, fc1b,
                                      fc2w, tsw, mask, c1s, c2s, c3s, tcs, rs, fs,
                                      ws, outp);
  } else {
    snn_main<<<32, 1024, 0, stream>>>(input, w1, b1, b2, b3, tcb, recb, fc1b,
                                      fc2w, tsw, mask, tcw, c1s, c2s, c3s, tcs, rs, fs,
                                      ws, outp);
  }
}

// Round 13
// 945.003 us; speedup vs baseline: 1.6910x; 1.6910x over previous
//
#include <hip/hip_runtime.h>

// CUBA Spiking CNN, B=32, T=100.
// R13: two-stage fence-free pipeline (64 blocks).
//  Stage A [0,32): conv1 + conv2 MFMA with kt-SPLIT (waves 0-7: kt 0-8,
//                  waves 8-15: kt 9-17; LDS reduce) -> each w2 frag read ONCE
//                  (288 KB/step, was 576). Pool -> nibbles, WT publish.
//  Stage C [32,64): tau=8 chunks. conv3 AND tc as f16 hi/lo MFMA with
//                  LDS-materialized A matrices (nibbles / spike bits expanded
//                  once per chunk). Streams 1.97MB per 8 steps (246 KB/step).
//                  Per-step core: {rec 8w || fc1(t-1) 8w} -> {LIF5 || LIF6+acc}.
// Shared-memory stages UNIONED in one 105KB buffer.

#define VTH 0.5f

// d_ws dword offsets
#define W2P_OFF  0
#define W3P_OFF  73728
#define TCP_OFF  368640
#define RECP_OFF 565248
#define FC1P_OFF 630784
#define WS_FLOATS 663552
#define P2G_OFF   WS_FLOATS
#define FLA_OFF   (P2G_OFF + 32 * 100 * 144)
#define FLAGS_N   800
#define WS_DW_END (FLA_OFF + FLAGS_N)
#define WS_NEED_BYTES ((size_t)WS_DW_END * 4)

typedef __attribute__((ext_vector_type(8))) _Float16 half8v;
typedef __attribute__((ext_vector_type(4))) float f32x4;

__device__ inline unsigned short f2h_bits(float x) {
  union { _Float16 h; unsigned short u; } c; c.h = (_Float16)x; return c.u;
}
__device__ inline float h2f(unsigned short u) {
  union { unsigned short u; _Float16 h; } c; c.u = u; return (float)c.h;
}

__global__ __launch_bounds__(256) void prep_weights(
    const float* __restrict__ w2, const float* __restrict__ w3,
    const float* __restrict__ tcw, const float* __restrict__ recw,
    const float* __restrict__ fc1w, float* __restrict__ ws)
{
  int idx = blockIdx.x * 256 + threadIdx.x;
  if (idx < W3P_OFF) {
    // conv2 f16 hi/lo fragments: frag=(kt*8+nt)*2+half
    int frag = idx >> 8, r = idx & 255;
    int lane = r >> 2, dw = r & 3;
    int half = frag & 1, nt = (frag >> 1) & 7, kt = frag >> 4;
    unsigned out = 0;
    #pragma unroll
    for (int j2 = 0; j2 < 2; ++j2) {
      int j = dw * 2 + j2;
      int oc = nt * 16 + (lane & 15);
      int k = kt * 32 + ((lane >> 4) << 3) + j;
      int c = k & 63, tap = k >> 6;
      float w = w2[(oc * 64 + c) * 9 + tap];
      unsigned short hb = f2h_bits(w);
      unsigned short bits = half ? f2h_bits((w - h2f(hb)) * 4096.f) : hb;
      out |= ((unsigned)bits) << (16 * j2);
    }
    ((unsigned*)ws)[idx] = out;
  } else if (idx < TCP_OFF) {
    // conv3 f16 hi/lo fragments: frag=(kt*16+nt)*2+half, kt 0..35
    int i = idx - W3P_OFF;
    int frag = i >> 8, r = i & 255;
    int lane = r >> 2, dwi = r & 3;
    int half = frag & 1, nt = (frag >> 1) & 15, kt = frag >> 5;
    unsigned out = 0;
    #pragma unroll
    for (int j2 = 0; j2 < 2; ++j2) {
      int j = dwi * 2 + j2;
      int oc = nt * 16 + (lane & 15);
      int k = kt * 32 + ((lane >> 4) << 3) + j;
      int c = k & 127, pos9 = k >> 7;
      float w = w3[(oc * 128 + c) * 9 + pos9];
      unsigned short hb = f2h_bits(w);
      unsigned short bits = half ? f2h_bits((w - h2f(hb)) * 4096.f) : hb;
      out |= ((unsigned)bits) << (16 * j2);
    }
    ((unsigned*)ws)[idx] = out;
  } else if (idx < RECP_OFF) {
    // tc f16 hi/lo fragments: frag=(kt*16+nt)*2+half, kt 0..23
    int i = idx - TCP_OFF;
    int frag = i >> 8, r = i & 255;
    int lane = r >> 2, dwi = r & 3;
    int half = frag & 1, nt = (frag >> 1) & 15, kt = frag >> 5;
    unsigned out = 0;
    #pragma unroll
    for (int j2 = 0; j2 < 2; ++j2) {
      int j = dwi * 2 + j2;
      int d = nt * 16 + (lane & 15);
      int kap = kt * 32 + ((lane >> 4) << 3) + j;
      int kk = kap >> 8, c = kap & 255;
      float w = tcw[(kk * 256 + d) * 256 + c];
      unsigned short hb = f2h_bits(w);
      unsigned short bits = half ? f2h_bits((w - h2f(hb)) * 4096.f) : hb;
      out |= ((unsigned)bits) << (16 * j2);
    }
    ((unsigned*)ws)[idx] = out;
  } else if (idx < FC1P_OFF) {
    int i = idx - RECP_OFF;
    int r = i & 3, dq = (i >> 2) & 63, c = i >> 8;
    ws[idx] = recw[(dq * 4 + r) * 256 + c];
  } else if (idx < WS_FLOATS) {
    int i = idx - FC1P_OFF;
    int r = i & 3, dq = (i >> 2) & 31, c = i >> 7;
    ws[idx] = fc1w[(dq * 4 + r) * 256 + c];
  }
}

__global__ __launch_bounds__(256) void zero_flags(float* __restrict__ ws) {
  int i = blockIdx.x * 256 + threadIdx.x;
  if (i < FLAGS_N) ((unsigned*)ws)[FLA_OFF + i] = 0u;
}

// ---------------------------------------------------------------------------
__global__ __launch_bounds__(1024, 4) void snn_pipe(
    const float* __restrict__ input, const float* __restrict__ w1g,
    const float* __restrict__ b1g, const float* __restrict__ b2g,
    const float* __restrict__ b3g, const float* __restrict__ tcbg,
    const float* __restrict__ recbg, const float* __restrict__ fc1bg,
    const float* __restrict__ fc2wg, const float* __restrict__ tswg,
    const float* __restrict__ maskg,
    const float* __restrict__ c1sg, const float* __restrict__ c2sg,
    const float* __restrict__ c3sg, const float* __restrict__ tcsg,
    const float* __restrict__ rsg, const float* __restrict__ fsg,
    float* __restrict__ ws, float* __restrict__ out)
{
  const int tid = threadIdx.x;
  const int wv  = tid >> 6;
  const int ln  = tid & 63;
  unsigned* p2g   = (unsigned*)ws + P2G_OFF;
  unsigned* flagA = (unsigned*)ws + FLA_OFF;
  const int b = blockIdx.x & 31;

  __shared__ __align__(16) char smem[107776];

  if (blockIdx.x < 32) {
    // ======================= STAGE A =======================================
    const half8v* w2h = (const half8v*)ws;
    char* s1b_c = smem;                                       // 10752 B
    unsigned short* s2b = (unsigned short*)(smem + 10752);    // 9216
    float* xt  = (float*)(smem + 19968);                      // 400
    float* b2L = (float*)(smem + 20368);                      // 512
    unsigned char* p2nb = (unsigned char*)(smem + 20880);     // 1152
    f32x4* red = (f32x4*)(smem + 22032);                      // 49152

    const int co = ln, pos0 = wv;
    const int g = wv >> 3;          // kt half-group
    const int nt2 = wv & 7;
    const int oc2 = nt2 * 16 + (ln & 15);
    float w1r[9];
    #pragma unroll
    for (int k = 0; k < 9; ++k) w1r[k] = w1g[co * 9 + k];
    const float b1r = b1g[co];
    float sp1[4], cur1[4], vol1[4];
    #pragma unroll
    for (int j = 0; j < 4; ++j) {
      int pos = pos0 + 16 * j;
      sp1[j]  = c1sg[((0 * 32 + b) * 64 + co) * 64 + pos];
      cur1[j] = c1sg[((1 * 32 + b) * 64 + co) * 64 + pos];
      vol1[j] = c1sg[((2 * 32 + b) * 64 + co) * 64 + pos];
    }
    int pyb[3];
    #pragma unroll
    for (int mt = 0; mt < 3; ++mt) {
      int p = mt * 16 + (ln & 15);
      pyb[mt] = (p < 36) ? ((p / 6) * 8 + (p % 6)) : 64;
    }
    // LIF2 state held by group 0 waves only
    float cur2[3][4], vol2[3][4];
    #pragma unroll
    for (int mt = 0; mt < 3; ++mt)
      #pragma unroll
      for (int r = 0; r < 4; ++r) {
        int p = mt * 16 + ((ln >> 4) << 2) + r;
        if (g == 0 && p < 36) {
          cur2[mt][r] = c2sg[((1 * 32 + b) * 128 + oc2) * 36 + p];
          vol2[mt][r] = c2sg[((2 * 32 + b) * 128 + oc2) * 36 + p];
        } else { cur2[mt][r] = 0.f; vol2[mt][r] = 0.f; }
      }
    if (tid < 128) b2L[tid] = b2g[tid];
    if (tid < 640) ((unsigned*)s1b_c)[2048 + tid] = 0u;  // zero rows 64..83
    __syncthreads();

    for (int t = 0; t < 100; ++t) {
      if (tid < 100) xt[tid] = input[(b * 100 + tid) * 100 + t];
      __syncthreads();

      // conv1 + LIF1
      #pragma unroll
      for (int j = 0; j < 4; ++j) {
        int pos = pos0 + 16 * j;
        int y = pos >> 3, x = pos & 7;
        float psp = b1r;
        #pragma unroll
        for (int kk = 0; kk < 9; ++kk) {
          int ky = kk / 3, kx = kk - ky * 3;
          psp = fmaf(xt[(y + ky) * 10 + x + kx], w1r[kk], psp);
        }
        float cur = 0.5f * cur1[j] + psp;
        float vol = 0.75f * vol1[j] * (1.f - sp1[j]) + cur;
        float sp  = (vol > VTH) ? 1.f : 0.f;
        cur1[j] = cur; vol1[j] = vol; sp1[j] = sp;
        unsigned short bits = (vol > VTH) ? (unsigned short)0x3C00 : (unsigned short)0;
        int byte = ((pos << 7) + (co << 1)) ^ ((pos & 7) << 4);
        *(unsigned short*)(s1b_c + byte) = bits;
      }
      __syncthreads();

      // conv2 MFMA, kt-split: each frag read by exactly one wave
      {
        f32x4 acc[3][2];
        #pragma unroll
        for (int mt = 0; mt < 3; ++mt) { acc[mt][0] = (f32x4){0,0,0,0}; acc[mt][1] = (f32x4){0,0,0,0}; }
        const int lnq16 = (ln >> 4) << 4;
        #pragma unroll
        for (int kt9 = 0; kt9 < 9; ++kt9) {
          const int kt = g * 9 + kt9;
          const int tap = kt >> 1;
          const int dpos = (tap / 3) * 8 + (tap % 3);
          const int c0b = ((kt & 1) << 6) + lnq16;
          half8v bh = w2h[(((kt << 3) + nt2) << 1) * 64 + ln];
          half8v bl = w2h[((((kt << 3) + nt2) << 1) + 1) * 64 + ln];
          #pragma unroll
          for (int mt = 0; mt < 3; ++mt) {
            int pos = pyb[mt] + dpos;
            int ab = ((pos << 7) + c0b) ^ ((pos & 7) << 4);
            half8v a = *(const half8v*)(s1b_c + ab);
            acc[mt][0] = __builtin_amdgcn_mfma_f32_16x16x32_f16(a, bh, acc[mt][0], 0, 0, 0);
            acc[mt][1] = __builtin_amdgcn_mfma_f32_16x16x32_f16(a, bl, acc[mt][1], 0, 0, 0);
          }
        }
        if (g == 1) {
          f32x4* rp = red + (nt2 * 64 + ln) * 6;
          #pragma unroll
          for (int mt = 0; mt < 3; ++mt) { rp[mt * 2] = acc[mt][0]; rp[mt * 2 + 1] = acc[mt][1]; }
        }
        __syncthreads();
        if (g == 0) {
          const f32x4* rp = red + (nt2 * 64 + ln) * 6;
          float bias2 = b2L[oc2];
          #pragma unroll
          for (int mt = 0; mt < 3; ++mt) {
            f32x4 hh = acc[mt][0] + rp[mt * 2];
            f32x4 llv = acc[mt][1] + rp[mt * 2 + 1];
            #pragma unroll
            for (int r = 0; r < 4; ++r) {
              int p = mt * 16 + ((ln >> 4) << 2) + r;
              if (p < 36) {
                float psp = hh[r] + 0.000244140625f * llv[r] + bias2;
                float spo = (vol2[mt][r] > VTH) ? 1.f : 0.f;
                float cur = 0.5f * cur2[mt][r] + psp;
                float vol = 0.75f * vol2[mt][r] * (1.f - spo) + cur;
                cur2[mt][r] = cur; vol2[mt][r] = vol;
                s2b[p * 128 + oc2] = (vol > VTH) ? (unsigned short)0x3C00 : (unsigned short)0;
              }
            }
          }
        }
      }
      __syncthreads();

      // pool: spike-count nibbles
      if (tid < 576) {
        int pp = tid >> 6, c0 = 2 * (tid & 63);
        int sy = (pp / 3) * 2, sx = (pp % 3) * 2;
        int n0 = (s2b[(sy * 6 + sx) * 128 + c0] != 0) + (s2b[(sy * 6 + sx + 1) * 128 + c0] != 0)
               + (s2b[((sy + 1) * 6 + sx) * 128 + c0] != 0) + (s2b[((sy + 1) * 6 + sx + 1) * 128 + c0] != 0);
        int c1 = c0 + 1;
        int n1 = (s2b[(sy * 6 + sx) * 128 + c1] != 0) + (s2b[(sy * 6 + sx + 1) * 128 + c1] != 0)
               + (s2b[((sy + 1) * 6 + sx) * 128 + c1] != 0) + (s2b[((sy + 1) * 6 + sx + 1) * 128 + c1] != 0);
        p2nb[pp * 128 + c0] = (unsigned char)n0;
        p2nb[pp * 128 + c1] = (unsigned char)n1;
      }
      __syncthreads();
      if (tid < 144) {
        unsigned dwv = 0;
        #pragma unroll
        for (int j = 0; j < 8; ++j)
          dwv |= ((unsigned)p2nb[8 * tid + j] & 0xFu) << (4 * j);
        __hip_atomic_store(&p2g[(b * 100 + t) * 144 + tid], dwv,
                           __ATOMIC_RELAXED, __HIP_MEMORY_SCOPE_AGENT);
      }
      if ((t & 3) == 3) {
        asm volatile("s_waitcnt vmcnt(0)" ::: "memory");
        __syncthreads();
        if (tid == 0)
          __hip_atomic_store(&flagA[b * 25 + (t >> 2)], 1u,
                             __ATOMIC_RELAXED, __HIP_MEMORY_SCOPE_AGENT);
      }
    }
  } else {
    // ======================= STAGE C =======================================
    const half8v* w3f  = (const half8v*)(ws + W3P_OFF);
    const half8v* tcf  = (const half8v*)(ws + TCP_OFF);
    const float4* recp = (const float4*)(ws + RECP_OFF);
    const float4* fc1p = (const float4*)(ws + FC1P_OFF);

    unsigned* prawL = (unsigned*)smem;                           // 4608
    unsigned short* Aldsu = (unsigned short*)(smem + 4608);      // 16x1160
    unsigned short* A2u   = (unsigned short*)(smem + 41728);     // 16x776
    float* psp3 = (float*)(smem + 66560);   // [8][256]
    float* psp4 = (float*)(smem + 74752);   // [8][256]
    float* scrR = (float*)(smem + 82944);   // [8][256]
    float* scrF = (float*)(smem + 91136);   // [16][128]
    float* b3L  = (float*)(smem + 99328);
    float* tcbL = (float*)(smem + 100352);
    float* recbL= (float*)(smem + 103424);
    float* fc1bL= (float*)(smem + 104448);
    float* fc2wL= (float*)(smem + 104960);
    float* maskL= (float*)(smem + 105984);
    float* tswL = (float*)(smem + 106496);
    unsigned* histQ = (unsigned*)(smem + 106896);                // [10][8]
    unsigned long long* s5B = (unsigned long long*)(smem + 107216);
    float* wpart = (float*)(smem + 107248);                      // [2][2]

    float c3sp = 0.f, c3cur = 0.f, c3vol = 0.f;
    float tcsp = 0.f, tccur = 0.f, tcvol = 0.f;
    float rspv = 0.f, rcur = 0.f, rvol = 0.f;
    float fsp = 0.f, fcur = 0.f, fvol = 0.f;
    float s4r[8] = {0,0,0,0,0,0,0,0};
    float accR0 = 0.f, accR1 = 0.f;

    if (tid < 256) {
      c3sp  = c3sg[(0 * 32 + b) * 256 + tid];
      c3cur = c3sg[(1 * 32 + b) * 256 + tid];
      c3vol = c3sg[(2 * 32 + b) * 256 + tid];
      tcsp  = tcsg[(0 * 32 + b) * 256 + tid];
      tccur = tcsg[(1 * 32 + b) * 256 + tid];
      tcvol = tcsg[(2 * 32 + b) * 256 + tid];
      rspv  = rsg[(0 * 32 + b) * 256 + tid];
      rcur  = rsg[(1 * 32 + b) * 256 + tid];
      rvol  = rsg[(2 * 32 + b) * 256 + tid];
      b3L[tid]   = b3g[tid];
      recbL[tid] = recbg[tid];
      tcbL[tid]       = tcbg[tid];
      tcbL[256 + tid] = tcbg[256 + tid];
      tcbL[512 + tid] = tcbg[512 + tid];
      unsigned long long bl = __ballot(rspv != 0.f);
      if (ln == 0) s5B[wv] = bl;
    } else if (tid < 384) {
      int d = tid - 256;
      fsp  = fsg[(0 * 32 + b) * 128 + d];
      fcur = fsg[(1 * 32 + b) * 128 + d];
      fvol = fsg[(2 * 32 + b) * 128 + d];
    }
    if (tid < 128) {
      fc1bL[tid] = fc1bg[tid];
      maskL[tid] = maskg[b * 128 + tid];
      fc2wL[tid]       = fc2wg[tid];
      fc2wL[128 + tid] = fc2wg[128 + tid];
    }
    if (tid < 100) tswL[tid] = tswg[tid];
    if (tid < 80) histQ[tid] = 0u;
    // zero A rows 8-15 (never rewritten)
    for (int i = tid; i < 4640; i += 1024) ((unsigned*)(Aldsu + 8 * 1160))[i] = 0u;
    for (int i = tid; i < 3104; i += 1024) ((unsigned*)(A2u + 8 * 776))[i] = 0u;
    __syncthreads();

    for (int t0 = 0; t0 < 100; t0 += 8) {
      const int ns = (100 - t0 < 8) ? (100 - t0) : 8;
      // ---- wait flag covering t0..t0+ns-1 ----
      if (tid == 0) {
        unsigned* f = &flagA[b * 25 + ((t0 + ns - 1) >> 2)];
        int guard = 0;
        while (__hip_atomic_load(f, __ATOMIC_RELAXED, __HIP_MEMORY_SCOPE_AGENT) == 0u) {
          __builtin_amdgcn_s_sleep(8);
          if (++guard > 4000000) break;
        }
      }
      __syncthreads();
      // hist ring shift (rows 0,1 <- 8,9)
      if (t0 > 0 && tid < 16) histQ[(tid >> 3) * 8 + (tid & 7)] = histQ[(8 + (tid >> 3)) * 8 + (tid & 7)];
      // load raw nibble dwords for ns steps
      for (int e = tid; e < 1152; e += 1024) {
        int s = e / 144, dw = e - s * 144;
        if (s < ns)
          prawL[e] = __hip_atomic_load(&p2g[((b * 100 + t0) + s) * 144 + dw],
                                       __ATOMIC_RELAXED, __HIP_MEMORY_SCOPE_AGENT);
      }
      __syncthreads();
      // expand nibbles -> A_lds f16 (rows 0..7)
      for (int e = tid; e < 9216; e += 1024) {
        int s = e / 1152, k = e - s * 1152;
        unsigned dv = prawL[s * 144 + (k >> 3)];
        int nib = (dv >> ((k & 7) * 4)) & 0xF;
        Aldsu[s * 1160 + k] = f2h_bits((float)nib * 0.25f);
      }
      __syncthreads();

      // ---- conv3 MFMA: M=8(pad16) N=256 K=1152, f16 hi/lo ----
      {
        f32x4 ach = {0,0,0,0}, acl = {0,0,0,0};
        const unsigned short* Arow = Aldsu + (ln & 15) * 1160 + ((ln >> 4) << 3);
        #pragma unroll
        for (int kt = 0; kt < 36; ++kt) {
          half8v a = *(const half8v*)(Arow + kt * 32);
          half8v bh = w3f[((kt * 16 + wv) * 2) * 64 + ln];
          half8v bl = w3f[((kt * 16 + wv) * 2 + 1) * 64 + ln];
          ach = __builtin_amdgcn_mfma_f32_16x16x32_f16(a, bh, ach, 0, 0, 0);
          acl = __builtin_amdgcn_mfma_f32_16x16x32_f16(a, bl, acl, 0, 0, 0);
        }
        if ((ln >> 4) < 2) {
          #pragma unroll
          for (int r = 0; r < 4; ++r) {
            int s = ((ln >> 4) << 2) + r;
            psp3[s * 256 + wv * 16 + (ln & 15)] = ach[r] + 0.000244140625f * acl[r];
          }
        }
      }
      __syncthreads();

      // ---- LIF3 x ns -> histQ rows 2..2+ns-1 ----
      if (tid < 256) {
        for (int s = 0; s < ns; ++s) {
          float cur = 0.5f * c3cur + (b3L[tid] + psp3[s * 256 + tid]);
          float vol = 0.75f * c3vol * (1.f - c3sp) + cur;
          float sp  = (vol > VTH) ? 1.f : 0.f;
          c3cur = cur; c3vol = vol; c3sp = sp;
          unsigned long long bl = __ballot(sp != 0.f);
          if (ln == 0) {
            histQ[(2 + s) * 8 + wv * 2]     = (unsigned)bl;
            histQ[(2 + s) * 8 + wv * 2 + 1] = (unsigned)(bl >> 32);
          }
        }
      }
      __syncthreads();

      // ---- build tc A matrix (8 x 768 f16) from hist bits ----
      for (int e = tid; e < 6144; e += 1024) {
        int s = e / 768, kap = e - s * 768;
        int kk = kap >> 8, c = kap & 255;
        unsigned bit = (histQ[(s + kk) * 8 + (c >> 5)] >> (c & 31)) & 1u;
        A2u[s * 776 + kap] = bit ? (unsigned short)0x3C00 : (unsigned short)0;
      }
      __syncthreads();

      // ---- tc MFMA: M=8(pad16) N=256 K=768 ----
      {
        f32x4 ach = {0,0,0,0}, acl = {0,0,0,0};
        const unsigned short* Arow = A2u + (ln & 15) * 776 + ((ln >> 4) << 3);
        #pragma unroll
        for (int kt = 0; kt < 24; ++kt) {
          half8v a = *(const half8v*)(Arow + kt * 32);
          half8v bh = tcf[((kt * 16 + wv) * 2) * 64 + ln];
          half8v bl = tcf[((kt * 16 + wv) * 2 + 1) * 64 + ln];
          ach = __builtin_amdgcn_mfma_f32_16x16x32_f16(a, bh, ach, 0, 0, 0);
          acl = __builtin_amdgcn_mfma_f32_16x16x32_f16(a, bl, acl, 0, 0, 0);
        }
        if ((ln >> 4) < 2) {
          #pragma unroll
          for (int r = 0; r < 4; ++r) {
            int s = ((ln >> 4) << 2) + r;
            psp4[s * 256 + wv * 16 + (ln & 15)] = ach[r] + 0.000244140625f * acl[r];
          }
        }
      }
      __syncthreads();

      // ---- LIF4 x ns -> s4r ----
      if (tid < 256) {
        for (int s = 0; s < ns; ++s) {
          int t = t0 + s;
          float sum = psp4[s * 256 + tid];
          #pragma unroll
          for (int kk = 0; kk < 3; ++kk)
            if (t >= 2 - kk) sum += tcbL[kk * 256 + tid];
          float cur = 0.5f * tccur + sum;
          float vol = 0.75f * tcvol * (1.f - tcsp) + cur;
          float sp  = (vol > VTH) ? 1.f : 0.f;
          tccur = cur; tcvol = vol; tcsp = sp;
          s4r[s] = sp;
        }
      }
      __syncthreads();

      // ---- per-step serial core ----
      for (int s = 0; s < ns; ++s) {
        int t = t0 + s;
        if (wv < 8) {
          int g = wv >> 1, h = wv & 1;
          unsigned m = (unsigned)(s5B[g] >> (h * 32));
          float4 a = {0.f, 0.f, 0.f, 0.f};
          while (m) {
            int bit = __builtin_ctz(m);
            m &= m - 1;
            float4 w4 = recp[(g * 64 + h * 32 + bit) * 64 + ln];
            a.x += w4.x; a.y += w4.y; a.z += w4.z; a.w += w4.w;
          }
          ((float4*)scrR)[wv * 64 + ln] = a;
        } else if (t > 0) {
          int g2 = wv - 8;
          unsigned m = (unsigned)(s5B[g2 >> 1] >> ((g2 & 1) * 32));
          int jj = ln >> 5, q = ln & 31, i = 0;
          float4 a = {0.f, 0.f, 0.f, 0.f};
          while (m) {
            int bit = __builtin_ctz(m);
            m &= m - 1;
            if ((i & 1) == jj) {
              float4 w4 = fc1p[(g2 * 32 + bit) * 32 + q];
              a.x += w4.x; a.y += w4.y; a.z += w4.z; a.w += w4.w;
            }
            ++i;
          }
          ((float4*)scrF)[(g2 * 2 + jj) * 32 + q] = a;
        }
        __syncthreads();
        if (tid < 256) {
          float r = s4r[s] + recbL[tid];
          #pragma unroll
          for (int w = 0; w < 8; ++w) r += scrR[w * 256 + tid];
          float cur = 0.5f * rcur + r;
          float vol = 0.75f * rvol * (1.f - rspv) + cur;
          float sp  = (vol > VTH) ? 1.f : 0.f;
          rcur = cur; rvol = vol; rspv = sp;
          unsigned long long bl = __ballot(sp != 0.f);
          if (ln == 0) s5B[wv] = bl;
        } else if (tid < 384 && t > 0) {
          int d = tid - 256;
          float sum = fc1bL[d];
          #pragma unroll
          for (int sl = 0; sl < 16; ++sl) sum += scrF[sl * 128 + d];
          float cur = (0.5f * fcur + sum) * maskL[d];
          float vol = 0.75f * fvol * (1.f - fsp) + cur;
          float sp  = (vol > VTH) ? 1.f : 0.f;
          fcur = cur; fvol = vol; fsp = sp;
          float v0 = sp * fc2wL[d];
          float v1 = sp * fc2wL[128 + d];
          #pragma unroll
          for (int off = 32; off > 0; off >>= 1) {
            v0 += __shfl_down(v0, off);
            v1 += __shfl_down(v1, off);
          }
          if (ln == 0) {
            float wt = tswL[t - 1];
            accR0 += wt * v0; accR1 += wt * v1;
          }
        }
        __syncthreads();
      }
    }

    // ---- epilogue: fc1 + LIF6 + acc for t = 99 ----
    if (wv >= 8) {
      int g2 = wv - 8;
      unsigned m = (unsigned)(s5B[g2 >> 1] >> ((g2 & 1) * 32));
      int jj = ln >> 5, q = ln & 31, i = 0;
      float4 a = {0.f, 0.f, 0.f, 0.f};
      while (m) {
        int bit = __builtin_ctz(m);
        m &= m - 1;
        if ((i & 1) == jj) {
          float4 w4 = fc1p[(g2 * 32 + bit) * 32 + q];
          a.x += w4.x; a.y += w4.y; a.z += w4.z; a.w += w4.w;
        }
        ++i;
      }
      ((float4*)scrF)[(g2 * 2 + jj) * 32 + q] = a;
    }
    __syncthreads();
    if (tid >= 256 && tid < 384) {
      int d = tid - 256;
      float sum = fc1bL[d];
      #pragma unroll
      for (int sl = 0; sl < 16; ++sl) sum += scrF[sl * 128 + d];
      float cur = (0.5f * fcur + sum) * maskL[d];
      float vol = 0.75f * fvol * (1.f - fsp) + cur;
      float sp  = (vol > VTH) ? 1.f : 0.f;
      float v0 = sp * fc2wL[d];
      float v1 = sp * fc2wL[128 + d];
      #pragma unroll
      for (int off = 32; off > 0; off >>= 1) {
        v0 += __shfl_down(v0, off);
        v1 += __shfl_down(v1, off);
      }
      if (ln == 0) {
        float wt = tswL[99];
        accR0 += wt * v0; accR1 += wt * v1;
        wpart[(wv - 4) * 2 + 0] = accR0; wpart[(wv - 4) * 2 + 1] = accR1;
      }
    }
    __syncthreads();
    if (tid < 2) out[b * 2 + tid] = wpart[tid] + wpart[2 + tid];
  }
}

extern "C" void kernel_launch(void* const* d_in, const int* in_sizes, int n_in,
                              void* d_out, int out_size, void* d_ws, size_t ws_size,
                              hipStream_t stream) {
  const float* input = (const float*)d_in[0];
  const float* w1    = (const float*)d_in[1];
  const float* b1    = (const float*)d_in[2];
  const float* w2    = (const float*)d_in[3];
  const float* b2    = (const float*)d_in[4];
  const float* w3    = (const float*)d_in[5];
  const float* b3    = (const float*)d_in[6];
  const float* tcw   = (const float*)d_in[7];
  const float* tcb   = (const float*)d_in[8];
  const float* recw  = (const float*)d_in[9];
  const float* recb  = (const float*)d_in[10];
  const float* fc1w  = (const float*)d_in[11];
  const float* fc1b  = (const float*)d_in[12];
  const float* fc2w  = (const float*)d_in[13];
  const float* tsw   = (const float*)d_in[14];
  const float* mask  = (const float*)d_in[15];
  const float* c1s   = (const float*)d_in[16];
  const float* c2s   = (const float*)d_in[17];
  const float* c3s   = (const float*)d_in[18];
  const float* tcs   = (const float*)d_in[19];
  const float* rs    = (const float*)d_in[20];
  const float* fs    = (const float*)d_in[21];
  float* ws   = (float*)d_ws;
  float* outp = (float*)d_out;

  prep_weights<<<WS_FLOATS / 256, 256, 0, stream>>>(w2, w3, tcw, recw, fc1w, ws);
  zero_flags<<<(FLAGS_N + 255) / 256, 256, 0, stream>>>(ws);
  snn_pipe<<<64, 1024, 0, stream>>>(input, w1, b1, b2, b3, tcb, recb, fc1b,
                                    fc2w, tsw, mask, c1s, c2s, c3s, tcs, rs, fs,
                                    ws, outp);
}